// Round 9
// baseline (1780.268 us; speedup 1.0000x reference)
//
#include <hip/hip_runtime.h>
#include <cmath>

// DHT: out[n,c,a,r] = sum over px (x,y) of feat[n,c,y,x],
//   r = rint((x-128)*cos(a deg) + (y-128)*sin(a deg)) + 361  (r in [180,542])
// feat[4,128,256,256] f32 -> out[4,128,180,723] f32.
//
// Locked-in findings:
//  R1-R4 (~31ms): LDS f32 atomicAdd serializes ~per-lane -> never on hot path.
//  R5 (2.69ms): wave-private rows + 4-col lane stride + plain program-ordered
//    DS RMW (race-free: lane bin spacing 4|coef|>=2.83 -> distinct bins).
//  R6 (3.88ms): >1 block/CU with chunked re-reads -> HBM-bound.
//  R7 (1.85ms): register-persistent px across ALL angles (FETCH 0.6GB);
//    model: 2.4M cyc DS-issue + 1.8M cyc bank conflicts.
//  R8 (1.66ms): quarter-split swizzle e=(b>>2)+(b&3)*96 cut conflicts 36%.
//    Residual: quarter offset 192 words == 0 mod 32 -> the 4 quarter clouds
//    overlap on identical banks; flush reads (lane-stride QW) 8-way.
//  R9: QW=100 (quarter word-offsets {0,8,16,24} mod 32 -> decorrelated);
//    flush iterates swizzled index e (stride-1, conflict-floor) and inverts
//    the swizzle for the output bin (b=4m+q; b>=368 rows are zero -> +0.0).

#define NA 180
#define NR 723
#define HW 65536
#define NC 512
#define CH 2            // angles per LDS chunk
#define ROW_W 368       // bins rl = r-RBASE in [4,366]
#define QW 100          // quarter width; word offset 200 == 8 mod 32
#define ROW_PAD 400     // 4 quarters x 100 (LDS rows: 16*2*400*8B = 100 KB)
#define RBASE 176
#define NWIN 32         // 8-px windows along the scan axis

__device__ __forceinline__ bool is_phase2(int a) { return a >= 46 && a <= 134; }

// bijective swizzle inside a 400-element row: e = (b>>2) + (b&3)*QW
__device__ __forceinline__ int swz(int b) { return (b >> 2) + (b & 3) * QW; }

// ---------------------------------------------------------------------------
// win[a][w][fast] u32 = base bin at scan=8w (bits 0..15), step bits 16..22.
// Phase-1 (a in [0,45]u[135,179]): fast=x, scan=y (step coef sin(a)>=0).
// Phase-2 (a in [46,134]):         fast=y, scan=x (step coef cos(a), sign
// flips at a=90). fp64 non-fused mul/add + rint bit-matches np.round
// (validated R1-R8: absmax 0.25 = f32 sum-order noise only).
// ---------------------------------------------------------------------------
__global__ __launch_bounds__(256) void dht_win(unsigned int* __restrict__ win) {
    const int lane = threadIdx.x;
    const int w = blockIdx.x;
    const int a = blockIdx.y;
    const double theta = (double)a * (M_PI / 180.0);
    const double c = cos(theta), s = sin(theta);
    const bool p2 = is_phase2(a);
    int prev = 0;
    unsigned int word = 0;
    #pragma unroll
    for (int i = 0; i < 8; ++i) {
        const int k = w * 8 + i;
        const int x = p2 ? k : lane;
        const int y = p2 ? lane : k;
        const double rho = __dadd_rn(__dmul_rn((double)(x - 128), c),
                                     __dmul_rn((double)(y - 128), s));
        int r = (int)rint(rho) + 361;
        r = min(max(r, 0), NR - 1);
        if (i == 0) word = (unsigned int)r;
        else if (r != prev) word |= (1u << (15 + i));
        prev = r;
    }
    win[((size_t)a * NWIN + w) * 256 + lane] = word;
}

__global__ __launch_bounds__(256) void zero_out(float4* __restrict__ o, int n4) {
    const int i = blockIdx.x * 256 + threadIdx.x;
    if (i < n4) o[i] = make_float4(0.f, 0.f, 0.f, 0.f);
}

// Branchless 8(scan) x 4(col) x 2(img) walk; concurrent lanes 4 columns
// apart -> bins >= 2.83 apart -> distinct (bijective swizzle preserves it).
template <int SGN>
__device__ __forceinline__ void walk2(const uint4 wq, const float2 (&px)[8][4],
                                      float2* __restrict__ rp) {
    #pragma unroll
    for (int j = 0; j < 4; ++j) {
        const unsigned int wrd = (&wq.x)[j];
        int bin = (int)(wrd & 0xffffu) - RBASE;
        #pragma unroll
        for (int k = 0; k < 8; ++k) {
            if (k) bin += SGN * (int)((wrd >> (15 + k)) & 1u);
            const int e = swz(bin);
            float2 v = rp[e];
            v.x += px[k][j].x;
            v.y += px[k][j].y;
            rp[e] = v;
        }
    }
}

// ---------------------------------------------------------------------------
// Block = (image-pair, phase, scan-half). 1024 thr = 16 waves; wave wv owns
// scan window w = 16h+wv (8 scan lines); lane owns 4 fast columns 4l..4l+3.
// px float2[8][4] loaded ONCE, reused across all angles of the phase.
// rows[16 waves][CH][ROW_PAD] float2 = 100 KB -> 1 block/CU.
// ---------------------------------------------------------------------------
__global__ __launch_bounds__(1024, 4) void dht_main(const float* __restrict__ feat,
                                                    const unsigned int* __restrict__ win,
                                                    float* __restrict__ out) {
    __shared__ float2 rows[16 * CH * ROW_PAD];   // 100 KB
    const int t = threadIdx.x;
    const int wv = t >> 6;
    const int l = t & 63;
    const int pair = blockIdx.x;
    const int phase = blockIdx.y;
    const int h = blockIdx.z;
    const int w = 16 * h + wv;          // scan window 0..31
    const int k0 = 8 * w;               // scan offset
    const float* __restrict__ f0 = feat + (size_t)(2 * pair) * HW;
    const float* __restrict__ f1 = feat + (size_t)(2 * pair + 1) * HW;
    float* __restrict__ o0 = out + (size_t)(2 * pair) * (NA * NR);
    float* __restrict__ o1 = out + (size_t)(2 * pair + 1) * (NA * NR);

    // ---- load persistent px tile: 8 scan x 4 col x 2 img ----
    float2 px[8][4];
    if (phase == 0) {
        // scan=y: rows y=k0+k, cols x=4l..4l+3 (fully coalesced float4)
        #pragma unroll
        for (int k = 0; k < 8; ++k) {
            const float4 a0 = *(const float4*)(f0 + ((k0 + k) << 8) + 4 * l);
            const float4 a1 = *(const float4*)(f1 + ((k0 + k) << 8) + 4 * l);
            px[k][0] = make_float2(a0.x, a1.x); px[k][1] = make_float2(a0.y, a1.y);
            px[k][2] = make_float2(a0.z, a1.z); px[k][3] = make_float2(a0.w, a1.w);
        }
    } else {
        // scan=x: rows y=4l+j, cols x=k0..k0+7 (2 aligned float4 per row/img)
        #pragma unroll
        for (int j = 0; j < 4; ++j) {
            const float4 b0 = *(const float4*)(f0 + ((4 * l + j) << 8) + k0);
            const float4 b1 = *(const float4*)(f0 + ((4 * l + j) << 8) + k0 + 4);
            const float4 c0 = *(const float4*)(f1 + ((4 * l + j) << 8) + k0);
            const float4 c1 = *(const float4*)(f1 + ((4 * l + j) << 8) + k0 + 4);
            px[0][j] = make_float2(b0.x, c0.x); px[1][j] = make_float2(b0.y, c0.y);
            px[2][j] = make_float2(b0.z, c0.z); px[3][j] = make_float2(b0.w, c0.w);
            px[4][j] = make_float2(b1.x, c1.x); px[5][j] = make_float2(b1.y, c1.y);
            px[6][j] = make_float2(b1.z, c1.z); px[7][j] = make_float2(b1.w, c1.w);
        }
    }

    const int nAng = phase ? 89 : 91;
    for (int cb = 0; cb < nAng; cb += CH) {
        const int cn = min(CH, nAng - cb);
        for (int i = t; i < 16 * CH * ROW_PAD; i += 1024)
            rows[i] = make_float2(0.f, 0.f);
        __syncthreads();

        for (int ai = 0; ai < cn; ++ai) {
            const int aidx = cb + ai;
            const int a = phase ? (46 + aidx) : (aidx <= 45 ? aidx : aidx + 89);
            const uint4 wq = *(const uint4*)(win + ((size_t)a * NWIN + w) * 256 + 4 * l);
            float2* __restrict__ rp = rows + (wv * CH + ai) * ROW_PAD;
            if (phase && a > 90) walk2<-1>(wq, px, rp);
            else                 walk2<+1>(wq, px, rp);
        }
        __syncthreads();

        // flush: iterate the SWIZZLED index e (lanes stride-1 -> conflict-
        // floor LDS reads); inverse-swizzle to the output bin b=4m+q.
        // b in [368,400) rows are never written (zero) -> harmless +0.0
        // (out col RBASE+b <= 575 < 723, pre-zeroed). Exactly-2 atomic
        // contributions per real out element -> deterministic.
        for (int i = t; i < cn * ROW_PAD; i += 1024) {
            const int al = i / ROW_PAD;
            const int e = i - al * ROW_PAD;
            const int q = e / QW;
            const int m = e - q * QW;
            const int b = 4 * m + q;
            float sx = 0.f, sy = 0.f;
            #pragma unroll
            for (int c2 = 0; c2 < 16; ++c2) {
                const float2 v = rows[(c2 * CH + al) * ROW_PAD + e];
                sx += v.x; sy += v.y;
            }
            const int aidx = cb + al;
            const int a = phase ? (46 + aidx) : (aidx <= 45 ? aidx : aidx + 89);
            const size_t o = (size_t)a * NR + (RBASE + b);
            unsafeAtomicAdd(o0 + o, sx);
            unsafeAtomicAdd(o1 + o, sy);
        }
        __syncthreads();
    }
}

extern "C" void kernel_launch(void* const* d_in, const int* in_sizes, int n_in,
                              void* d_out, int out_size, void* d_ws, size_t ws_size,
                              hipStream_t stream) {
    const float* feat = (const float*)d_in[0];
    float* out = (float*)d_out;
    unsigned int* win = (unsigned int*)d_ws;

    const size_t win_bytes = (size_t)NA * NWIN * 256 * sizeof(unsigned int); // 5.9MB
    if (ws_size < win_bytes) return;

    const int n4 = out_size / 4;   // out_size = 512*180*723, divisible by 4
    hipLaunchKernelGGL(zero_out, dim3((n4 + 255) / 256), dim3(256), 0, stream,
                       (float4*)out, n4);
    hipLaunchKernelGGL(dht_win, dim3(NWIN, NA), dim3(256), 0, stream, win);
    hipLaunchKernelGGL(dht_main, dim3(NC / 2, 2, 2), dim3(1024), 0, stream,
                       feat, win, out);
}

// Round 10
// 1755.832 us; speedup vs baseline: 1.0139x; 1.0139x over previous
//
#include <hip/hip_runtime.h>
#include <cmath>

// DHT: out[n,c,a,r] = sum over px (x,y) of feat[n,c,y,x],
//   r = rint((x-128)*cos(a deg) + (y-128)*sin(a deg)) + 361  (r in [180,542])
// feat[4,128,256,256] f32 -> out[4,128,180,723] f32.
//
// Locked-in findings:
//  R1-R4 (~31ms): LDS f32 atomicAdd serializes ~per-lane -> never on hot path.
//  R5 (2.69ms): wave-private rows + 4-col lane stride + plain program-ordered
//    DS RMW (race-free: lane bin spacing 4|coef|>=2.83 -> distinct bins).
//  R6 (3.88ms): >1 block/CU with chunked re-reads -> HBM-bound.
//  R7 (1.85ms): register-persistent px across ALL angles (FETCH 0.6GB).
//  R8 (1.66ms): quarter swizzle e=(b>>2)+(b&3)*96, conflicts -36%. Model:
//    LDS PORT bytes bound: 369K b64-RMW-pairs/CU x 1024B/128B = 2.95M cyc
//    + 1.1M conflict cyc.
//  R9 (1.84ms, REVERTED): QW=100 worsened walk conflicts (bank micro-models
//    keep mispredicting -> keep R8 empirically); inverse-swizzle flush
//    scattered global atomics (WRITE 322MB->1.2GB).
//  R10: masked RUN-MERGE. LDS port cost scales with ACTIVE lanes; merging
//    runs per-lane (write only at step-bit boundaries) cuts active RMW
//    traffic to ~45% (E[writes/8px] = 1+7*E[coef2] ~ 3.6). R5's rejection
//    was about wave-op COUNT; port BYTES do drop.

#define NA 180
#define NR 723
#define HW 65536
#define NC 512
#define CH 2            // angles per LDS chunk
#define ROW_W 368       // bins rl = r-RBASE in [4,366]
#define ROW_PAD 384     // 4 quarters x 96 (R8 empirical best)
#define QW 96
#define RBASE 176
#define NWIN 32         // 8-px windows along the scan axis

__device__ __forceinline__ bool is_phase2(int a) { return a >= 46 && a <= 134; }

// bijective swizzle inside a 384-element row (R8 config)
__device__ __forceinline__ int swz(int b) { return (b >> 2) + (b & 3) * QW; }

// ---------------------------------------------------------------------------
// win[a][w][fast] u32 = base bin at scan=8w (bits 0..15), step bits 16..22.
// Phase-1 (a in [0,45]u[135,179]): fast=x, scan=y (step coef sin(a)>=0).
// Phase-2 (a in [46,134]):         fast=y, scan=x (step coef cos(a), sign
// flips at a=90). fp64 non-fused mul/add + rint bit-matches np.round
// (validated R1-R9: absmax 0.25 = f32 sum-order noise only).
// ---------------------------------------------------------------------------
__global__ __launch_bounds__(256) void dht_win(unsigned int* __restrict__ win) {
    const int lane = threadIdx.x;
    const int w = blockIdx.x;
    const int a = blockIdx.y;
    const double theta = (double)a * (M_PI / 180.0);
    const double c = cos(theta), s = sin(theta);
    const bool p2 = is_phase2(a);
    int prev = 0;
    unsigned int word = 0;
    #pragma unroll
    for (int i = 0; i < 8; ++i) {
        const int k = w * 8 + i;
        const int x = p2 ? k : lane;
        const int y = p2 ? lane : k;
        const double rho = __dadd_rn(__dmul_rn((double)(x - 128), c),
                                     __dmul_rn((double)(y - 128), s));
        int r = (int)rint(rho) + 361;
        r = min(max(r, 0), NR - 1);
        if (i == 0) word = (unsigned int)r;
        else if (r != prev) word |= (1u << (15 + i));
        prev = r;
    }
    win[((size_t)a * NWIN + w) * 256 + lane] = word;
}

__global__ __launch_bounds__(256) void zero_out(float4* __restrict__ o, int n4) {
    const int i = blockIdx.x * 256 + threadIdx.x;
    if (i < n4) o[i] = make_float4(0.f, 0.f, 0.f, 0.f);
}

// Run-merged 8(scan) x 4(col) x 2(img) walk. RMW only at run boundaries
// (exec-masked) -> ~45% of the active-lane LDS port traffic. Race-free:
// active subsets of an all-distinct-bin lane set remain distinct; same-wave
// DS ops stay program-ordered.
template <int SGN>
__device__ __forceinline__ void walk2(const uint4 wq, const float2 (&px)[8][4],
                                      float2* __restrict__ rp) {
    #pragma unroll
    for (int j = 0; j < 4; ++j) {
        const unsigned int wrd = (&wq.x)[j];
        int bin = (int)(wrd & 0xffffu) - RBASE;
        float2 cur = px[0][j];
        #pragma unroll
        for (int k = 1; k < 8; ++k) {
            if ((wrd >> (15 + k)) & 1u) {
                const int e = swz(bin);
                float2 v = rp[e];
                v.x += cur.x; v.y += cur.y;
                rp[e] = v;                       // run boundary: flush run-sum
                bin += SGN;
                cur = px[k][j];
            } else {
                cur.x += px[k][j].x;             // extend run in registers
                cur.y += px[k][j].y;
            }
        }
        const int e = swz(bin);
        float2 v = rp[e];
        v.x += cur.x; v.y += cur.y;
        rp[e] = v;                               // final run of the window
    }
}

// ---------------------------------------------------------------------------
// Block = (image-pair, phase, scan-half). 1024 thr = 16 waves; wave wv owns
// scan window w = 16h+wv (8 scan lines); lane owns 4 fast columns 4l..4l+3.
// px float2[8][4] loaded ONCE, reused across all angles of the phase.
// rows[16 waves][CH][ROW_PAD] float2 = 96 KB -> 1 block/CU.
// ---------------------------------------------------------------------------
__global__ __launch_bounds__(1024, 4) void dht_main(const float* __restrict__ feat,
                                                    const unsigned int* __restrict__ win,
                                                    float* __restrict__ out) {
    __shared__ float2 rows[16 * CH * ROW_PAD];   // 96 KB
    const int t = threadIdx.x;
    const int wv = t >> 6;
    const int l = t & 63;
    const int pair = blockIdx.x;
    const int phase = blockIdx.y;
    const int h = blockIdx.z;
    const int w = 16 * h + wv;          // scan window 0..31
    const int k0 = 8 * w;               // scan offset
    const float* __restrict__ f0 = feat + (size_t)(2 * pair) * HW;
    const float* __restrict__ f1 = feat + (size_t)(2 * pair + 1) * HW;
    float* __restrict__ o0 = out + (size_t)(2 * pair) * (NA * NR);
    float* __restrict__ o1 = out + (size_t)(2 * pair + 1) * (NA * NR);

    // ---- load persistent px tile: 8 scan x 4 col x 2 img ----
    float2 px[8][4];
    if (phase == 0) {
        // scan=y: rows y=k0+k, cols x=4l..4l+3 (fully coalesced float4)
        #pragma unroll
        for (int k = 0; k < 8; ++k) {
            const float4 a0 = *(const float4*)(f0 + ((k0 + k) << 8) + 4 * l);
            const float4 a1 = *(const float4*)(f1 + ((k0 + k) << 8) + 4 * l);
            px[k][0] = make_float2(a0.x, a1.x); px[k][1] = make_float2(a0.y, a1.y);
            px[k][2] = make_float2(a0.z, a1.z); px[k][3] = make_float2(a0.w, a1.w);
        }
    } else {
        // scan=x: rows y=4l+j, cols x=k0..k0+7 (2 aligned float4 per row/img)
        #pragma unroll
        for (int j = 0; j < 4; ++j) {
            const float4 b0 = *(const float4*)(f0 + ((4 * l + j) << 8) + k0);
            const float4 b1 = *(const float4*)(f0 + ((4 * l + j) << 8) + k0 + 4);
            const float4 c0 = *(const float4*)(f1 + ((4 * l + j) << 8) + k0);
            const float4 c1 = *(const float4*)(f1 + ((4 * l + j) << 8) + k0 + 4);
            px[0][j] = make_float2(b0.x, c0.x); px[1][j] = make_float2(b0.y, c0.y);
            px[2][j] = make_float2(b0.z, c0.z); px[3][j] = make_float2(b0.w, c0.w);
            px[4][j] = make_float2(b1.x, c1.x); px[5][j] = make_float2(b1.y, c1.y);
            px[6][j] = make_float2(b1.z, c1.z); px[7][j] = make_float2(b1.w, c1.w);
        }
    }

    const int nAng = phase ? 89 : 91;
    for (int cb = 0; cb < nAng; cb += CH) {
        const int cn = min(CH, nAng - cb);
        for (int i = t; i < 16 * CH * ROW_PAD; i += 1024)
            rows[i] = make_float2(0.f, 0.f);
        __syncthreads();

        for (int ai = 0; ai < cn; ++ai) {
            const int aidx = cb + ai;
            const int a = phase ? (46 + aidx) : (aidx <= 45 ? aidx : aidx + 89);
            const uint4 wq = *(const uint4*)(win + ((size_t)a * NWIN + w) * 256 + 4 * l);
            float2* __restrict__ rp = rows + (wv * CH + ai) * ROW_PAD;
            if (phase && a > 90) walk2<-1>(wq, px, rp);
            else                 walk2<+1>(wq, px, rp);
        }
        __syncthreads();

        // flush (R8 form): lanes iterate rl contiguously -> contiguous global
        // atomics; LDS read at swz(rl) (conflicted but cheap, ~0.4M cyc).
        // Exactly-2 atomic contributions per out element -> deterministic.
        for (int i = t; i < cn * ROW_W; i += 1024) {
            const int al = i / ROW_W;
            const int rl = i - al * ROW_W;
            const int ad = swz(rl);
            float sx = 0.f, sy = 0.f;
            #pragma unroll
            for (int c2 = 0; c2 < 16; ++c2) {
                const float2 v = rows[(c2 * CH + al) * ROW_PAD + ad];
                sx += v.x; sy += v.y;
            }
            const int aidx = cb + al;
            const int a = phase ? (46 + aidx) : (aidx <= 45 ? aidx : aidx + 89);
            const size_t o = (size_t)a * NR + (RBASE + rl);
            unsafeAtomicAdd(o0 + o, sx);
            unsafeAtomicAdd(o1 + o, sy);
        }
        __syncthreads();
    }
}

extern "C" void kernel_launch(void* const* d_in, const int* in_sizes, int n_in,
                              void* d_out, int out_size, void* d_ws, size_t ws_size,
                              hipStream_t stream) {
    const float* feat = (const float*)d_in[0];
    float* out = (float*)d_out;
    unsigned int* win = (unsigned int*)d_ws;

    const size_t win_bytes = (size_t)NA * NWIN * 256 * sizeof(unsigned int); // 5.9MB
    if (ws_size < win_bytes) return;

    const int n4 = out_size / 4;   // out_size = 512*180*723, divisible by 4
    hipLaunchKernelGGL(zero_out, dim3((n4 + 255) / 256), dim3(256), 0, stream,
                       (float4*)out, n4);
    hipLaunchKernelGGL(dht_win, dim3(NWIN, NA), dim3(256), 0, stream, win);
    hipLaunchKernelGGL(dht_main, dim3(NC / 2, 2, 2), dim3(1024), 0, stream,
                       feat, win, out);
}